// Round 1
// baseline (615.636 us; speedup 1.0000x reference)
//
#include <hip/hip_runtime.h>
#include <hip/hip_bf16.h>

// ---------------- types / helpers ----------------
using bf16x8 = __attribute__((ext_vector_type(8))) short;
using f32x4  = __attribute__((ext_vector_type(4))) float;

__device__ __forceinline__ unsigned short f2bf_rne(float x) {
    unsigned u = __float_as_uint(x);
    u += 0x7fffu + ((u >> 16) & 1u);
    return (unsigned short)(u >> 16);
}
__device__ __forceinline__ float bflo(unsigned v) { return __uint_as_float(v << 16); }
__device__ __forceinline__ float bfhi(unsigned v) { return __uint_as_float(v & 0xffff0000u); }

// ---------------- workspace layout (bytes) ----------------
constexpr size_t OFF_C1D = 0;                                  // [4096][4][256] f32 conv1(data), no bias
constexpr size_t OFF_Q1  = OFF_C1D + (size_t)4096 * 1024 * 4;  // [32][4][256] f32 conv1(proto)-b1
constexpr size_t OFF_BT  = OFF_Q1  + (size_t)32 * 1024 * 4;    // [1024][8192] bf16, pre-swizzled B^T
constexpr size_t OFF_FSI = OFF_BT  + (size_t)1024 * 8192 * 2;  // [32][4096] f32 fs_ini^T
constexpr size_t OFF_FS  = OFF_FSI + (size_t)32 * 4096 * 4;    // [32][4096] f32 fs^T
constexpr size_t OFF_ASC = OFF_FS  + (size_t)32 * 4096 * 4;    // [4096][8192] bf16, pre-swizzled A
// total = ~102 MB

// ---------------- kernel 1: conv1(data) (no bias), padded L stride 256 ----------------
__global__ __launch_bounds__(256) void k_prep_data(const float* __restrict__ data,
                                                   const float* __restrict__ w1,
                                                   float* __restrict__ c1dp) {
    __shared__ float ds[256];
    __shared__ float w1s[20];
    int b = blockIdx.x, tid = threadIdx.x;
    ds[tid] = data[b * 256 + tid];
    if (tid < 20) w1s[tid] = w1[tid];
    __syncthreads();
    if (tid < 254) {
#pragma unroll
        for (int c = 0; c < 4; ++c) {
            float s = 0.f;
#pragma unroll
            for (int k = 0; k < 5; ++k) {
                int x = tid + k - 1;
                float xv = (x >= 0 && x < 256) ? ds[x] : 0.f;
                s += w1s[c * 5 + k] * xv;
            }
            c1dp[b * 1024 + c * 256 + tid] = s;
        }
    }
}

// ---------------- kernel 2: q1 = conv1(proto) - b1 ----------------
__global__ __launch_bounds__(256) void k_prep_proto(const float* __restrict__ proto,
                                                    const float* __restrict__ w1,
                                                    const float* __restrict__ b1,
                                                    float* __restrict__ q1p) {
    __shared__ float ps[256];
    __shared__ float w1s[20];
    int r = blockIdx.x, tid = threadIdx.x;
    ps[tid] = proto[r * 256 + tid];
    if (tid < 20) w1s[tid] = w1[tid];
    __syncthreads();
    if (tid < 254) {
#pragma unroll
        for (int c = 0; c < 4; ++c) {
            float s = -b1[c];
#pragma unroll
            for (int k = 0; k < 5; ++k) {
                int x = tid + k - 1;
                float xv = (x >= 0 && x < 256) ? ps[x] : 0.f;
                s += w1s[c * 5 + k] * xv;
            }
            q1p[r * 1024 + c * 256 + tid] = s;
        }
    }
}

// ---------------- kernel 3: B^T cast, zero-pad cols 1000..1023, pre-swizzled ----------------
// BT logical [c][k]; storage: 16B chunk index within each 128B block XORed with (c&7)
__global__ __launch_bounds__(256) void k_castB(const float* __restrict__ cw,
                                               unsigned short* __restrict__ BT) {
    int g = blockIdx.x * 256 + threadIdx.x;   // 1,048,576 = 8192 k * 128 c-groups
    int k = g & 8191;
    int c0 = (g >> 13) << 3;
#pragma unroll
    for (int i = 0; i < 8; ++i) {
        int c = c0 + i;
        float v = (c < 1000) ? cw[k * 1000 + c] : 0.f;
        int byte = c * 16384 + ((k >> 6) << 7) + (((((k >> 3) & 7)) ^ (c & 7)) << 4) + ((k & 7) << 1);
        *(unsigned short*)((char*)BT + byte) = f2bf_rne(v);
    }
}

// ---------------- kernel 4: gating net (pool1 -> conv2 -> pool2 -> fc1 -> fc2 -> tanh) ----------------
// grid 2048: bid>>6 = r, (bid&63)*64 = base b. 4 waves, each 16 samples.
__global__ __launch_bounds__(256) void k_gating(const float* __restrict__ c1dp,
                                                const float* __restrict__ q1p,
                                                const float* __restrict__ w2,
                                                const float* __restrict__ b2,
                                                const float* __restrict__ fc1w,
                                                const float* __restrict__ fc1b,
                                                const float* __restrict__ fc2w,
                                                const float* __restrict__ fc2b,
                                                float* __restrict__ fsiniT) {
    __shared__ unsigned short W1[30752];   // fc1_w bf16, [f][o] (o-major rows of 124)
    __shared__ float q1s[1024];
    __shared__ float w2s[80];
    __shared__ float b2s[4];
    __shared__ float fc1bs[124];
    __shared__ float fc2ws[124];
    __shared__ float p1buf[4][512];        // per-wave pooled1 [c][128], j<127 valid
    __shared__ float hbuf[4][256];         // per-wave h [248]

    int tid = threadIdx.x, w = tid >> 6, lane = tid & 63;
    int r = blockIdx.x >> 6;
    int bb0 = (blockIdx.x & 63) << 6;

    for (int i = tid; i < 30752; i += 256) W1[i] = f2bf_rne(fc1w[i]);
    for (int i = tid; i < 1024; i += 256) q1s[i] = q1p[r * 1024 + i];
    if (tid < 80) w2s[tid] = w2[tid];
    if (tid < 4) b2s[tid] = b2[tid];
    if (tid < 124) { fc1bs[tid] = fc1b[tid]; fc2ws[tid] = fc2w[tid]; }
    __syncthreads();

    const unsigned int* W1u = (const unsigned int*)W1;

    for (int i = 0; i < 16; ++i) {
        int b = bb0 + (w << 4) + i;
        const float* crow = c1dp + b * 1024;
        // phase 1: relu(c1d - q1) -> avgpool2 -> pooled1[c][j], j<127
#pragma unroll
        for (int c = 0; c < 4; ++c) {
#pragma unroll
            for (int jj = 0; jj < 2; ++jj) {
                int j = jj * 64 + lane;
                if (j < 127) {
                    float t0 = crow[c * 256 + 2 * j] - q1s[c * 256 + 2 * j];
                    float t1 = crow[c * 256 + 2 * j + 1] - q1s[c * 256 + 2 * j + 1];
                    t0 = t0 > 0.f ? t0 : 0.f;
                    t1 = t1 > 0.f ? t1 : 0.f;
                    p1buf[w][c * 128 + j] = 0.5f * (t0 + t1);
                }
            }
        }
        __syncthreads();
        // phase 2: conv2 + b2, relu, avgpool2 -> h[c*62+j2]
        {
            int j2 = lane;
            if (j2 < 62) {
#pragma unroll
                for (int c = 0; c < 4; ++c) {
                    float u0 = b2s[c], u1 = b2s[c];
#pragma unroll
                    for (int ci = 0; ci < 4; ++ci) {
#pragma unroll
                        for (int k = 0; k < 5; ++k) {
                            float wv = w2s[(c * 4 + ci) * 5 + k];
                            int l0 = 2 * j2 + k - 1;
                            float p0 = (l0 >= 0 && l0 < 127) ? p1buf[w][ci * 128 + l0] : 0.f;
                            int l1 = l0 + 1;
                            float p1v = (l1 < 127) ? p1buf[w][ci * 128 + l1] : 0.f;
                            u0 += wv * p0;
                            u1 += wv * p1v;
                        }
                    }
                    u0 = u0 > 0.f ? u0 : 0.f;
                    u1 = u1 > 0.f ? u1 : 0.f;
                    hbuf[w][c * 62 + j2] = 0.5f * (u0 + u1);
                }
            }
        }
        __syncthreads();
        // phase 3: fc1 (bf16 weights from LDS) + relu, fc2 dot, tanh
        float acc0 = 0.f, acc1 = 0.f;
        if (lane < 62) {
            for (int f = 0; f < 248; ++f) {
                float hv = hbuf[w][f];
                unsigned pw = W1u[f * 62 + lane];
                acc0 += hv * bflo(pw);
                acc1 += hv * bfhi(pw);
            }
        }
        float z = 0.f;
        if (lane < 62) {
            float h0 = acc0 + fc1bs[2 * lane];
            float h1 = acc1 + fc1bs[2 * lane + 1];
            h0 = h0 > 0.f ? h0 : 0.f;
            h1 = h1 > 0.f ? h1 : 0.f;
            z = h0 * fc2ws[2 * lane] + h1 * fc2ws[2 * lane + 1];
        }
#pragma unroll
        for (int off = 32; off >= 1; off >>= 1) z += __shfl_xor(z, off, 64);
        if (lane == 0) fsiniT[r * 4096 + b] = tanhf(z + fc2b[0]);
        __syncthreads();
    }
}

// ---------------- kernel 5: softmax over rules ----------------
__global__ __launch_bounds__(256) void k_softmax(const float* __restrict__ fsiniT,
                                                 float* __restrict__ fsT) {
    int b = blockIdx.x * 256 + threadIdx.x;  // 4096
    float v[32];
    float m = -1e30f;
#pragma unroll
    for (int r = 0; r < 32; ++r) { v[r] = fsiniT[r * 4096 + b]; m = fmaxf(m, v[r]); }
    float s = 0.f;
#pragma unroll
    for (int r = 0; r < 32; ++r) { v[r] = expf(v[r] - m); s += v[r]; }
    float inv = 1.f / s;
#pragma unroll
    for (int r = 0; r < 32; ++r) fsT[r * 4096 + b] = v[r] * inv;
}

// ---------------- kernel 6: A[b][k] = bf16(fs[b,r]*data[b,f]), pre-swizzled ----------------
__global__ __launch_bounds__(256) void k_scaleA(const float* __restrict__ data,
                                                const float* __restrict__ fsT,
                                                unsigned short* __restrict__ Asc) {
    int g = blockIdx.x * 256 + threadIdx.x;  // 4,194,304 = 4096 b * 1024 kg
    int b = g >> 10, kg = g & 1023;
    int r = kg >> 5, f0 = (kg & 31) << 3;
    float fs = fsT[r * 4096 + b];
    const float4* dp = (const float4*)(data + b * 256 + f0);
    float4 v0 = dp[0], v1 = dp[1];
    float vals[8] = {v0.x, v0.y, v0.z, v0.w, v1.x, v1.y, v1.z, v1.w};
    uint4 o;
    unsigned* op = (unsigned*)&o;
#pragma unroll
    for (int i = 0; i < 4; ++i) {
        unsigned lo = f2bf_rne(vals[2 * i] * fs);
        unsigned hi = f2bf_rne(vals[2 * i + 1] * fs);
        op[i] = lo | (hi << 16);
    }
    int byte = b * 16384 + ((kg & ~7) << 4) + (((kg & 7) ^ (b & 7)) << 4);
    *(uint4*)((char*)Asc + byte) = o;
}

// ---------------- kernel 7: GEMM [4096 x 8192] x [8192 x 1024] + fs@consq_b epilogue ----------------
// 128x128 tile, BK=64, 512 threads (8 waves, 2x4), 16x16x32 bf16 MFMA.
// LDS tiles land pre-swizzled (linear copy of pre-swizzled ws); ds_read applies XOR (row&7)<<4.
__global__ __launch_bounds__(512) void k_gemm(const unsigned short* __restrict__ Asc,
                                              const unsigned short* __restrict__ BT,
                                              const float* __restrict__ fsT,
                                              const float* __restrict__ cb,
                                              float* __restrict__ out) {
    __shared__ unsigned short As[8192];  // 128 rows x 64 k bf16 (swizzled)
    __shared__ unsigned short Bs[8192];  // 128 cols x 64 k bf16 (swizzled)
    int tid = threadIdx.x, lane = tid & 63, w = tid >> 6;
    int wm = w >> 2, wn = w & 3;
    int mt = blockIdx.x >> 3, nt = blockIdx.x & 7;
    int row0 = mt << 7, col0 = nt << 7;

    f32x4 acc[4][2] = {};

    const char* Ab = (const char*)Asc;
    const char* Bb = (const char*)BT;
    int flat0 = tid * 16, flat1 = tid * 16 + 8192;
    int rowl0 = flat0 >> 7, colB0 = flat0 & 127;
    int rowl1 = flat1 >> 7, colB1 = flat1 & 127;
    const char* aSrc0 = Ab + (row0 + rowl0) * 16384 + colB0;
    const char* aSrc1 = Ab + (row0 + rowl1) * 16384 + colB1;
    const char* bSrc0 = Bb + (col0 + rowl0) * 16384 + colB0;
    const char* bSrc1 = Bb + (col0 + rowl1) * 16384 + colB1;

    uint4 ra0 = *(const uint4*)aSrc0, ra1 = *(const uint4*)aSrc1;
    uint4 rb0 = *(const uint4*)bSrc0, rb1 = *(const uint4*)bSrc1;

    for (int kt = 0; kt < 128; ++kt) {
        __syncthreads();
        *(uint4*)((char*)As + flat0) = ra0;
        *(uint4*)((char*)As + flat1) = ra1;
        *(uint4*)((char*)Bs + flat0) = rb0;
        *(uint4*)((char*)Bs + flat1) = rb1;
        if (kt < 127) {
            int off = (kt + 1) << 7;  // 64 k * 2B per step
            ra0 = *(const uint4*)(aSrc0 + off);
            ra1 = *(const uint4*)(aSrc1 + off);
            rb0 = *(const uint4*)(bSrc0 + off);
            rb1 = *(const uint4*)(bSrc1 + off);
        }
        __syncthreads();
#pragma unroll
        for (int s = 0; s < 2; ++s) {
            bf16x8 af[4], bfv[2];
            int colByte = ((s << 5) + ((lane >> 4) << 3)) << 1;
#pragma unroll
            for (int mi = 0; mi < 4; ++mi) {
                int rowA = (wm << 6) + (mi << 4) + (lane & 15);
                int byte = (rowA << 7) + colByte;
                af[mi] = *(const bf16x8*)((const char*)As + (byte ^ ((rowA & 7) << 4)));
            }
#pragma unroll
            for (int ni = 0; ni < 2; ++ni) {
                int rowB = (wn << 5) + (ni << 4) + (lane & 15);
                int byte = (rowB << 7) + colByte;
                bfv[ni] = *(const bf16x8*)((const char*)Bs + (byte ^ ((rowB & 7) << 4)));
            }
#pragma unroll
            for (int mi = 0; mi < 4; ++mi)
#pragma unroll
                for (int ni = 0; ni < 2; ++ni)
                    acc[mi][ni] = __builtin_amdgcn_mfma_f32_16x16x32_bf16(af[mi], bfv[ni], acc[mi][ni], 0, 0, 0);
        }
    }

    // epilogue: bias[row,col] = sum_r fs[b,r]*consq_b[r,c], then store
    int cA = col0 + (wn << 5) + (lane & 15);
    int cB2 = cA + 16;
    int rbase = row0 + (wm << 6) + ((lane >> 4) << 2);
    float bias[4][4][2];
#pragma unroll
    for (int mi = 0; mi < 4; ++mi)
#pragma unroll
        for (int q = 0; q < 4; ++q) { bias[mi][q][0] = 0.f; bias[mi][q][1] = 0.f; }

    for (int rr = 0; rr < 32; ++rr) {
        float cb0 = (cA < 1000) ? cb[rr * 1000 + cA] : 0.f;
        float cb1 = (cB2 < 1000) ? cb[rr * 1000 + cB2] : 0.f;
        const float* fcol = fsT + rr * 4096;
#pragma unroll
        for (int mi = 0; mi < 4; ++mi)
#pragma unroll
            for (int q = 0; q < 4; ++q) {
                float fsv = fcol[rbase + mi * 16 + q];
                bias[mi][q][0] += fsv * cb0;
                bias[mi][q][1] += fsv * cb1;
            }
    }
#pragma unroll
    for (int mi = 0; mi < 4; ++mi)
#pragma unroll
        for (int q = 0; q < 4; ++q) {
            int row = rbase + mi * 16 + q;
            if (cA < 1000) out[row * 1000 + cA] = acc[mi][0][q] + bias[mi][q][0];
            if (cB2 < 1000) out[row * 1000 + cB2] = acc[mi][1][q] + bias[mi][q][1];
        }
}

// ---------------- launch ----------------
extern "C" void kernel_launch(void* const* d_in, const int* in_sizes, int n_in,
                              void* d_out, int out_size, void* d_ws, size_t ws_size,
                              hipStream_t stream) {
    const float* data  = (const float*)d_in[0];
    const float* proto = (const float*)d_in[1];
    const float* w1    = (const float*)d_in[2];
    const float* b1    = (const float*)d_in[3];
    const float* w2    = (const float*)d_in[4];
    const float* b2    = (const float*)d_in[5];
    const float* fc1w  = (const float*)d_in[6];
    const float* fc1b  = (const float*)d_in[7];
    const float* fc2w  = (const float*)d_in[8];
    const float* fc2b  = (const float*)d_in[9];
    const float* cw    = (const float*)d_in[10];
    const float* cbias = (const float*)d_in[11];
    float* out = (float*)d_out;
    char* ws = (char*)d_ws;

    float* c1dp            = (float*)(ws + OFF_C1D);
    float* q1p             = (float*)(ws + OFF_Q1);
    unsigned short* BT     = (unsigned short*)(ws + OFF_BT);
    float* fsiniT          = (float*)(ws + OFF_FSI);
    float* fsT             = (float*)(ws + OFF_FS);
    unsigned short* Asc    = (unsigned short*)(ws + OFF_ASC);

    hipLaunchKernelGGL(k_prep_data, dim3(4096), dim3(256), 0, stream, data, w1, c1dp);
    hipLaunchKernelGGL(k_prep_proto, dim3(32), dim3(256), 0, stream, proto, w1, b1, q1p);
    hipLaunchKernelGGL(k_castB, dim3(4096), dim3(256), 0, stream, cw, BT);
    hipLaunchKernelGGL(k_gating, dim3(2048), dim3(256), 0, stream,
                       c1dp, q1p, w2, b2, fc1w, fc1b, fc2w, fc2b, fsiniT);
    hipLaunchKernelGGL(k_softmax, dim3(16), dim3(256), 0, stream, fsiniT, fsT);
    hipLaunchKernelGGL(k_scaleA, dim3(16384), dim3(256), 0, stream, data, fsT, Asc);
    hipLaunchKernelGGL(k_gemm, dim3(256), dim3(512), 0, stream, Asc, BT, fsT, cbias, out);
}

// Round 2
// 314.081 us; speedup vs baseline: 1.9601x; 1.9601x over previous
//
#include <hip/hip_runtime.h>
#include <hip/hip_bf16.h>

// ---------------- types / helpers ----------------
using bf16x8 = __attribute__((ext_vector_type(8))) short;
using f32x4  = __attribute__((ext_vector_type(4))) float;

__device__ __forceinline__ unsigned short f2bf_rne(float x) {
    unsigned u = __float_as_uint(x);
    u += 0x7fffu + ((u >> 16) & 1u);
    return (unsigned short)(u >> 16);
}

// ---------------- workspace layout (bytes) ----------------
constexpr size_t OFF_DT  = 0;                                   // [256][4096] f32 dataT
constexpr size_t OFF_Q1  = OFF_DT  + (size_t)256 * 4096 * 4;    // [32][4][256] f32 conv1(proto)-b1
constexpr size_t OFF_BT  = OFF_Q1  + (size_t)32 * 1024 * 4;     // [1024][8192] bf16, pre-swizzled B^T
constexpr size_t OFF_W1S = OFF_BT  + (size_t)1024 * 8192 * 2;   // [128][256] bf16, pre-swizzled fc1_w
constexpr size_t OFF_FSI = OFF_W1S + (size_t)128 * 256 * 2;     // [32][4096] f32 fs_ini^T (flat srow)
constexpr size_t OFF_FS  = OFF_FSI + (size_t)32 * 4096 * 4;     // [32][4096] f32 fs^T
constexpr size_t OFF_ASC = OFF_FS  + (size_t)32 * 4096 * 4;     // [4096][8192] bf16 A (aliases h2!)
constexpr size_t OFF_H2  = OFF_ASC;                             // [131072][256] bf16 h2 (dead before scaleA)
// total ~85 MB

// ---------------- kernel: transpose data [4096][256] -> dataT [256][4096] ----------------
__global__ __launch_bounds__(256) void k_transpose(const float* __restrict__ data,
                                                   float* __restrict__ dataT) {
    __shared__ float tile[64][65];
    int bx = blockIdx.x & 63;   // b-tile
    int fx = blockIdx.x >> 6;   // f-tile
    int tx = threadIdx.x & 63, ty4 = threadIdx.x >> 6;
#pragma unroll
    for (int i = 0; i < 16; ++i) {
        int ty = ty4 * 16 + i;
        tile[ty][tx] = data[(bx * 64 + ty) * 256 + fx * 64 + tx];
    }
    __syncthreads();
#pragma unroll
    for (int i = 0; i < 16; ++i) {
        int ty = ty4 * 16 + i;
        dataT[(fx * 64 + ty) * 4096 + bx * 64 + tx] = tile[tx][ty];
    }
}

// ---------------- kernel: q1 = conv1(proto) - b1 ----------------
__global__ __launch_bounds__(256) void k_prep_proto(const float* __restrict__ proto,
                                                    const float* __restrict__ w1,
                                                    const float* __restrict__ b1,
                                                    float* __restrict__ q1p) {
    __shared__ float ps[256];
    __shared__ float w1s[20];
    int r = blockIdx.x, tid = threadIdx.x;
    ps[tid] = proto[r * 256 + tid];
    if (tid < 20) w1s[tid] = w1[tid];
    __syncthreads();
    if (tid < 254) {
#pragma unroll
        for (int c = 0; c < 4; ++c) {
            float s = -b1[c];
#pragma unroll
            for (int k = 0; k < 5; ++k) {
                int x = tid + k - 1;
                float xv = (x >= 0 && x < 256) ? ps[x] : 0.f;
                s += w1s[c * 5 + k] * xv;
            }
            q1p[r * 1024 + c * 256 + tid] = s;
        }
    }
}

// ---------------- kernel: B^T cast, zero-pad cols 1000..1023, pre-swizzled ----------------
__global__ __launch_bounds__(256) void k_castB(const float* __restrict__ cw,
                                               unsigned short* __restrict__ BT) {
    int g = blockIdx.x * 256 + threadIdx.x;   // 1,048,576 = 8192 k * 128 c-groups
    int k = g & 8191;
    int c0 = (g >> 13) << 3;
#pragma unroll
    for (int i = 0; i < 8; ++i) {
        int c = c0 + i;
        float v = (c < 1000) ? cw[k * 1000 + c] : 0.f;
        int byte = c * 16384 + ((k >> 6) << 7) + (((((k >> 3) & 7)) ^ (c & 7)) << 4) + ((k & 7) << 1);
        *(unsigned short*)((char*)BT + byte) = f2bf_rne(v);
    }
}

// ---------------- kernel: fc1_w cast -> [128 col][256 k] bf16 pre-swizzled ----------------
// k-permutation: k = j2*4 + c  <->  f_att = (k&3)*62 + (k>>2)
__global__ __launch_bounds__(256) void k_castW(const float* __restrict__ fc1w,
                                               unsigned short* __restrict__ W1s) {
    int idx = blockIdx.x * 256 + threadIdx.x;  // 32768
    int col = idx >> 8, k = idx & 255;
    float v = 0.f;
    if (col < 124 && k < 248) {
        int f = (k & 3) * 62 + (k >> 2);
        v = fc1w[f * 124 + col];
    }
    int byte = col * 512 + ((k >> 6) << 7) + ((((k >> 3) & 7) ^ (col & 7)) << 4) + ((k & 7) << 1);
    *(unsigned short*)((char*)W1s + byte) = f2bf_rne(v);
}

// ---------------- kernel: gating conv (sample-per-lane) -> h2 bf16 pre-swizzled ----------------
// wave job = (r, b-chunk of 64). grid 512 x 256 (2048 wave jobs). Zero __syncthreads.
__global__ __launch_bounds__(256) void k_conv(const float* __restrict__ dataT,
                                              const float* __restrict__ q1p,
                                              const float* __restrict__ w2,
                                              const float* __restrict__ b2,
                                              char* __restrict__ h2c) {
    __shared__ unsigned short Tsh[4 * 64 * 72];   // per-wave [64 samples][72 k] bf16 (pad to 144B rows)

    int tid = threadIdx.x, lane = tid & 63, w = tid >> 6;
    int job = blockIdx.x * 4 + w;
    int r  = __builtin_amdgcn_readfirstlane(job >> 6);
    int b0 = __builtin_amdgcn_readfirstlane((job & 63) << 6);
    int b = b0 + lane;
    int rb0 = r * 4096 + b0;
    unsigned short* T = Tsh + w * (64 * 72);

    // weights in registers (wave-uniform -> compiler may promote to SGPR)
    float w1r[20], w2r[80], b2r[4];
#pragma unroll
    for (int i = 0; i < 20; ++i) w1r[i] = w2 ? 0.f : 0.f;  // placeholder overwritten below
    // (separate loops to keep uniform loads simple)
    {
        const float* w1g = q1p - 0;  // dummy init removed below
    }
#pragma unroll
    for (int i = 0; i < 80; ++i) w2r[i] = w2[i];
#pragma unroll
    for (int i = 0; i < 4; ++i) b2r[i] = b2[i];

    const float* q1row = q1p + r * 1024;

    // conv1 weights come in via dataT's sibling input; pass w1 through q1p? No — w1 passed separately:
    // (handled: see k_conv2 wrapper below)
    (void)w1r;

    // --- the real body is in k_conv_impl; this kernel is replaced below ---
    (void)T; (void)b; (void)rb0; (void)q1row; (void)h2c; (void)dataT; (void)b2r;
}

// NOTE: k_conv above was a stale scaffold; the real kernel (with w1 arg) follows.
__global__ __launch_bounds__(256) void k_conv2(const float* __restrict__ dataT,
                                               const float* __restrict__ q1p,
                                               const float* __restrict__ w1,
                                               const float* __restrict__ w2,
                                               const float* __restrict__ b2,
                                               char* __restrict__ h2c) {
    __shared__ unsigned short Tsh[4 * 64 * 72];

    int tid = threadIdx.x, lane = tid & 63, w = tid >> 6;
    int job = blockIdx.x * 4 + w;
    int r  = __builtin_amdgcn_readfirstlane(job >> 6);
    int b0 = __builtin_amdgcn_readfirstlane((job & 63) << 6);
    int b = b0 + lane;
    int rb0 = r * 4096 + b0;
    unsigned short* T = Tsh + w * (64 * 72);

    float w1r[20], w2r[80], b2r[4];
#pragma unroll
    for (int i = 0; i < 20; ++i) w1r[i] = w1[i];
#pragma unroll
    for (int i = 0; i < 80; ++i) w2r[i] = w2[i];
#pragma unroll
    for (int i = 0; i < 4; ++i) b2r[i] = b2[i];
    const float* q1row = q1p + r * 1024;

    // pooled1(l) for all 4 channels: on-the-fly conv1 from dataT, minus q1, relu, avgpool2
    auto pooled_one = [&](int l, float out4[4]) {
        float d[6];
#pragma unroll
        for (int i = 0; i < 6; ++i) {
            int f = 2 * l - 1 + i;
            d[i] = (f >= 0 && f < 256) ? dataT[f * 4096 + b] : 0.f;
        }
#pragma unroll
        for (int c = 0; c < 4; ++c) {
            float s0 = 0.f, s1 = 0.f;
#pragma unroll
            for (int k = 0; k < 5; ++k) {
                s0 += w1r[c * 5 + k] * d[k];
                s1 += w1r[c * 5 + k] * d[k + 1];
            }
            float q0 = q1row[c * 256 + 2 * l];
            float q1v = q1row[c * 256 + 2 * l + 1];
            float t0 = fmaxf(s0 - q0, 0.f);
            float t1 = fmaxf(s1 - q1v, 0.f);
            out4[c] = 0.5f * (t0 + t1);
        }
    };

    // rolling window p[ci][0..5] = pooled1[2*j2-1 .. 2*j2+4] (index -1 = pad 0)
    float p[4][6];
#pragma unroll
    for (int c = 0; c < 4; ++c) p[c][0] = 0.f;
    for (int l = 0; l < 5; ++l) {
        float pv[4];
        pooled_one(l, pv);
#pragma unroll
        for (int c = 0; c < 4; ++c) p[c][l + 1] = pv[c];
    }

#pragma unroll 1
    for (int j2 = 0; j2 < 62; ++j2) {
        // conv2 (+b2) at t=2j2, 2j2+1; relu; avgpool2
        float u0[4], u1[4];
#pragma unroll
        for (int c = 0; c < 4; ++c) { u0[c] = b2r[c]; u1[c] = b2r[c]; }
#pragma unroll
        for (int c = 0; c < 4; ++c)
#pragma unroll
            for (int ci = 0; ci < 4; ++ci)
#pragma unroll
                for (int k = 0; k < 5; ++k) {
                    float wv = w2r[(c * 4 + ci) * 5 + k];
                    u0[c] += wv * p[ci][k];
                    u1[c] += wv * p[ci][k + 1];
                }
        unsigned pk0, pk1;
        {
            float h0 = 0.5f * (fmaxf(u0[0], 0.f) + fmaxf(u1[0], 0.f));
            float h1 = 0.5f * (fmaxf(u0[1], 0.f) + fmaxf(u1[1], 0.f));
            float h2v = 0.5f * (fmaxf(u0[2], 0.f) + fmaxf(u1[2], 0.f));
            float h3 = 0.5f * (fmaxf(u0[3], 0.f) + fmaxf(u1[3], 0.f));
            pk0 = (unsigned)f2bf_rne(h0) | ((unsigned)f2bf_rne(h1) << 16);
            pk1 = (unsigned)f2bf_rne(h2v) | ((unsigned)f2bf_rne(h3) << 16);
        }
        // k-index = j2*4 + c ; write into per-wave LDS tile at col (j2&15)*4
        {
            uint2 vv; vv.x = pk0; vv.y = pk1;
            *(uint2*)(T + lane * 72 + (j2 & 15) * 4) = vv;
        }
        // flush every 16 j2 (k-chunk of 64), pre-swizzled global rows
        if (j2 == 61) {
            // zero-pad k 248..255 (cols 56..63)
            uint4 z; z.x = z.y = z.z = z.w = 0u;
            *(uint4*)(T + lane * 72 + 56) = z;
        }
        if ((j2 & 15) == 15 || j2 == 61) {
            int chunk = j2 >> 4;
            int g = lane & 7;
#pragma unroll
            for (int i = 0; i < 8; ++i) {
                int sL = i * 8 + (lane >> 3);
                bf16x8 v = *(const bf16x8*)(T + sL * 72 + g * 8);
                int srow = rb0 + sL;
                size_t byte = (size_t)srow * 512 + (size_t)(chunk * 128) + (size_t)((g ^ (srow & 7)) << 4);
                *(bf16x8*)(h2c + byte) = v;
            }
        }
        // advance window: shift 2, compute pooled1 l = 2j2+5, 2j2+6
        if (j2 < 61) {
#pragma unroll
            for (int c = 0; c < 4; ++c) {
                p[c][0] = p[c][2]; p[c][1] = p[c][3];
                p[c][2] = p[c][4]; p[c][3] = p[c][5];
            }
            float pv[4];
            pooled_one(2 * j2 + 5, pv);
#pragma unroll
            for (int c = 0; c < 4; ++c) p[c][4] = pv[c];
            pooled_one(2 * j2 + 6, pv);
#pragma unroll
            for (int c = 0; c < 4; ++c) p[c][5] = pv[c];
        }
    }
}

// ---------------- kernel: fc1+relu+fc2+tanh as register MFMA GEMM ----------------
// [131072 x 256pad] x [256pad x 128pad]; A from pre-swizzled h2, B from pre-swizzled W1s.
// No LDS, no barriers. Epilogue: fc2 dot via shfl reduce -> fsiniT[srow].
__global__ __launch_bounds__(256) void k_fc(const char* __restrict__ h2,
                                            const char* __restrict__ W1s,
                                            const float* __restrict__ fc1b,
                                            const float* __restrict__ fc2w,
                                            const float* __restrict__ fc2b,
                                            float* __restrict__ fsiniT) {
    int tid = threadIdx.x, lane = tid & 63, w = tid >> 6;
    int row0 = blockIdx.x * 128 + w * 32;
    int lr = lane & 15, g = lane >> 4, rxor = lr & 7;

    f32x4 acc[2][8] = {};

    const char* arow0 = h2 + (size_t)(row0 + lr) * 512;
    const char* arow1 = arow0 + 16 * 512;

    auto inrowf = [&](int ks) {
        return ((ks >> 1) << 7) + ((((ks * 4 + g) & 7) ^ rxor) << 4);
    };

    bf16x8 a0 = *(const bf16x8*)(arow0 + inrowf(0));
    bf16x8 a1 = *(const bf16x8*)(arow1 + inrowf(0));

#pragma unroll
    for (int ks = 0; ks < 8; ++ks) {
        int ir = inrowf(ks);
        bf16x8 bfr[8];
#pragma unroll
        for (int nf = 0; nf < 8; ++nf)
            bfr[nf] = *(const bf16x8*)(W1s + (nf * 16 + lr) * 512 + ir);
        bf16x8 an0 = a0, an1 = a1;
        if (ks < 7) {
            int ir2 = inrowf(ks + 1);
            an0 = *(const bf16x8*)(arow0 + ir2);
            an1 = *(const bf16x8*)(arow1 + ir2);
        }
#pragma unroll
        for (int nf = 0; nf < 8; ++nf) {
            acc[0][nf] = __builtin_amdgcn_mfma_f32_16x16x32_bf16(a0, bfr[nf], acc[0][nf], 0, 0, 0);
            acc[1][nf] = __builtin_amdgcn_mfma_f32_16x16x32_bf16(a1, bfr[nf], acc[1][nf], 0, 0, 0);
        }
        a0 = an0; a1 = an1;
    }

    // epilogue: h = relu(acc + fc1b[col]); z = sum_col h * fc2w[col]; tanh(z + fc2b)
    float zp[2][4] = {};
#pragma unroll
    for (int nf = 0; nf < 8; ++nf) {
        int col = nf * 16 + lr;
        float b1v = (col < 124) ? fc1b[col] : 0.f;
        float w2v = (col < 124) ? fc2w[col] : 0.f;
#pragma unroll
        for (int mf = 0; mf < 2; ++mf)
#pragma unroll
            for (int q = 0; q < 4; ++q) {
                float h = fmaxf(acc[mf][nf][q] + b1v, 0.f);
                zp[mf][q] += h * w2v;
            }
    }
#pragma unroll
    for (int off = 1; off < 16; off <<= 1) {
#pragma unroll
        for (int mf = 0; mf < 2; ++mf)
#pragma unroll
            for (int q = 0; q < 4; ++q)
                zp[mf][q] += __shfl_xor(zp[mf][q], off, 64);
    }
    if (lr == 0) {
        float c2 = fc2b[0];
#pragma unroll
        for (int mf = 0; mf < 2; ++mf)
#pragma unroll
            for (int q = 0; q < 4; ++q) {
                int srow = row0 + mf * 16 + g * 4 + q;
                fsiniT[srow] = tanhf(zp[mf][q] + c2);
            }
    }
}

// ---------------- kernel: softmax over rules ----------------
__global__ __launch_bounds__(256) void k_softmax(const float* __restrict__ fsiniT,
                                                 float* __restrict__ fsT) {
    int b = blockIdx.x * 256 + threadIdx.x;  // 4096
    float v[32];
    float m = -1e30f;
#pragma unroll
    for (int r = 0; r < 32; ++r) { v[r] = fsiniT[r * 4096 + b]; m = fmaxf(m, v[r]); }
    float s = 0.f;
#pragma unroll
    for (int r = 0; r < 32; ++r) { v[r] = expf(v[r] - m); s += v[r]; }
    float inv = 1.f / s;
#pragma unroll
    for (int r = 0; r < 32; ++r) fsT[r * 4096 + b] = v[r] * inv;
}

// ---------------- kernel: A[b][k] = bf16(fs[b,r]*data[b,f]), pre-swizzled ----------------
__global__ __launch_bounds__(256) void k_scaleA(const float* __restrict__ data,
                                                const float* __restrict__ fsT,
                                                unsigned short* __restrict__ Asc) {
    int g = blockIdx.x * 256 + threadIdx.x;  // 4,194,304 = 4096 b * 1024 kg
    int b = g >> 10, kg = g & 1023;
    int r = kg >> 5, f0 = (kg & 31) << 3;
    float fs = fsT[r * 4096 + b];
    const float4* dp = (const float4*)(data + b * 256 + f0);
    float4 v0 = dp[0], v1 = dp[1];
    float vals[8] = {v0.x, v0.y, v0.z, v0.w, v1.x, v1.y, v1.z, v1.w};
    uint4 o;
    unsigned* op = (unsigned*)&o;
#pragma unroll
    for (int i = 0; i < 4; ++i) {
        unsigned lo = f2bf_rne(vals[2 * i] * fs);
        unsigned hi = f2bf_rne(vals[2 * i + 1] * fs);
        op[i] = lo | (hi << 16);
    }
    int byte = b * 16384 + ((kg & ~7) << 4) + (((kg & 7) ^ (b & 7)) << 4);
    *(uint4*)((char*)Asc + byte) = o;
}

// ---------------- kernel: GEMM [4096 x 8192] x [8192 x 1024] + fs@consq_b epilogue ----------------
__global__ __launch_bounds__(512) void k_gemm(const unsigned short* __restrict__ Asc,
                                              const unsigned short* __restrict__ BT,
                                              const float* __restrict__ fsT,
                                              const float* __restrict__ cb,
                                              float* __restrict__ out) {
    __shared__ unsigned short As[8192];  // 128 rows x 64 k bf16 (swizzled)
    __shared__ unsigned short Bs[8192];  // 128 cols x 64 k bf16 (swizzled)
    int tid = threadIdx.x, lane = tid & 63, w = tid >> 6;
    int wm = w >> 2, wn = w & 3;
    int mt = blockIdx.x >> 3, nt = blockIdx.x & 7;
    int row0 = mt << 7, col0 = nt << 7;

    f32x4 acc[4][2] = {};

    const char* Ab = (const char*)Asc;
    const char* Bb = (const char*)BT;
    int flat0 = tid * 16, flat1 = tid * 16 + 8192;
    int rowl0 = flat0 >> 7, colB0 = flat0 & 127;
    int rowl1 = flat1 >> 7, colB1 = flat1 & 127;
    const char* aSrc0 = Ab + (row0 + rowl0) * 16384 + colB0;
    const char* aSrc1 = Ab + (row0 + rowl1) * 16384 + colB1;
    const char* bSrc0 = Bb + (col0 + rowl0) * 16384 + colB0;
    const char* bSrc1 = Bb + (col0 + rowl1) * 16384 + colB1;

    uint4 ra0 = *(const uint4*)aSrc0, ra1 = *(const uint4*)aSrc1;
    uint4 rb0 = *(const uint4*)bSrc0, rb1 = *(const uint4*)bSrc1;

    for (int kt = 0; kt < 128; ++kt) {
        __syncthreads();
        *(uint4*)((char*)As + flat0) = ra0;
        *(uint4*)((char*)As + flat1) = ra1;
        *(uint4*)((char*)Bs + flat0) = rb0;
        *(uint4*)((char*)Bs + flat1) = rb1;
        if (kt < 127) {
            int off = (kt + 1) << 7;
            ra0 = *(const uint4*)(aSrc0 + off);
            ra1 = *(const uint4*)(aSrc1 + off);
            rb0 = *(const uint4*)(bSrc0 + off);
            rb1 = *(const uint4*)(bSrc1 + off);
        }
        __syncthreads();
#pragma unroll
        for (int s = 0; s < 2; ++s) {
            bf16x8 af[4], bfv[2];
            int colByte = ((s << 5) + ((lane >> 4) << 3)) << 1;
#pragma unroll
            for (int mi = 0; mi < 4; ++mi) {
                int rowA = (wm << 6) + (mi << 4) + (lane & 15);
                int byte = (rowA << 7) + colByte;
                af[mi] = *(const bf16x8*)((const char*)As + (byte ^ ((rowA & 7) << 4)));
            }
#pragma unroll
            for (int ni = 0; ni < 2; ++ni) {
                int rowB = (wn << 5) + (ni << 4) + (lane & 15);
                int byte = (rowB << 7) + colByte;
                bfv[ni] = *(const bf16x8*)((const char*)Bs + (byte ^ ((rowB & 7) << 4)));
            }
#pragma unroll
            for (int mi = 0; mi < 4; ++mi)
#pragma unroll
                for (int ni = 0; ni < 2; ++ni)
                    acc[mi][ni] = __builtin_amdgcn_mfma_f32_16x16x32_bf16(af[mi], bfv[ni], acc[mi][ni], 0, 0, 0);
        }
    }

    int cA = col0 + (wn << 5) + (lane & 15);
    int cB2 = cA + 16;
    int rbase = row0 + (wm << 6) + ((lane >> 4) << 2);
    float bias[4][4][2];
#pragma unroll
    for (int mi = 0; mi < 4; ++mi)
#pragma unroll
        for (int q = 0; q < 4; ++q) { bias[mi][q][0] = 0.f; bias[mi][q][1] = 0.f; }

    for (int rr = 0; rr < 32; ++rr) {
        float cb0 = (cA < 1000) ? cb[rr * 1000 + cA] : 0.f;
        float cb1 = (cB2 < 1000) ? cb[rr * 1000 + cB2] : 0.f;
        const float* fcol = fsT + rr * 4096;
#pragma unroll
        for (int mi = 0; mi < 4; ++mi)
#pragma unroll
            for (int q = 0; q < 4; ++q) {
                float fsv = fcol[rbase + mi * 16 + q];
                bias[mi][q][0] += fsv * cb0;
                bias[mi][q][1] += fsv * cb1;
            }
    }
#pragma unroll
    for (int mi = 0; mi < 4; ++mi)
#pragma unroll
        for (int q = 0; q < 4; ++q) {
            int row = rbase + mi * 16 + q;
            if (cA < 1000) out[row * 1000 + cA] = acc[mi][0][q] + bias[mi][q][0];
            if (cB2 < 1000) out[row * 1000 + cB2] = acc[mi][1][q] + bias[mi][q][1];
        }
}

// ---------------- launch ----------------
extern "C" void kernel_launch(void* const* d_in, const int* in_sizes, int n_in,
                              void* d_out, int out_size, void* d_ws, size_t ws_size,
                              hipStream_t stream) {
    const float* data  = (const float*)d_in[0];
    const float* proto = (const float*)d_in[1];
    const float* w1    = (const float*)d_in[2];
    const float* b1    = (const float*)d_in[3];
    const float* w2    = (const float*)d_in[4];
    const float* b2    = (const float*)d_in[5];
    const float* fc1w  = (const float*)d_in[6];
    const float* fc1b  = (const float*)d_in[7];
    const float* fc2w  = (const float*)d_in[8];
    const float* fc2b  = (const float*)d_in[9];
    const float* cw    = (const float*)d_in[10];
    const float* cbias = (const float*)d_in[11];
    float* out = (float*)d_out;
    char* ws = (char*)d_ws;

    float* dataT           = (float*)(ws + OFF_DT);
    float* q1p             = (float*)(ws + OFF_Q1);
    unsigned short* BT     = (unsigned short*)(ws + OFF_BT);
    unsigned short* W1s    = (unsigned short*)(ws + OFF_W1S);
    float* fsiniT          = (float*)(ws + OFF_FSI);
    float* fsT             = (float*)(ws + OFF_FS);
    unsigned short* Asc    = (unsigned short*)(ws + OFF_ASC);
    char* h2c              = (char*)(ws + OFF_H2);

    hipLaunchKernelGGL(k_transpose, dim3(256), dim3(256), 0, stream, data, dataT);
    hipLaunchKernelGGL(k_prep_proto, dim3(32), dim3(256), 0, stream, proto, w1, b1, q1p);
    hipLaunchKernelGGL(k_castB, dim3(4096), dim3(256), 0, stream, cw, BT);
    hipLaunchKernelGGL(k_castW, dim3(128), dim3(256), 0, stream, fc1w, W1s);
    hipLaunchKernelGGL(k_conv2, dim3(512), dim3(256), 0, stream, dataT, q1p, w1, w2, b2, h2c);
    hipLaunchKernelGGL(k_fc, dim3(1024), dim3(256), 0, stream,
                       h2c, (const char*)W1s, fc1b, fc2w, fc2b, fsiniT);
    hipLaunchKernelGGL(k_softmax, dim3(16), dim3(256), 0, stream, fsiniT, fsT);
    hipLaunchKernelGGL(k_scaleA, dim3(16384), dim3(256), 0, stream, data, fsT, Asc);
    hipLaunchKernelGGL(k_gemm, dim3(256), dim3(512), 0, stream, Asc, BT, fsT, cbias, out);
}